// Round 9
// baseline (232.834 us; speedup 1.0000x reference)
//
#include <hip/hip_runtime.h>
#include <hip/hip_bf16.h>
#include <math.h>

#define N_IN   48
#define N_HID  16
#define N_CLS  8
#define NB_SHIFT 9       // bucket = dst >> 9  (512 nodes/bucket)
#define TILE   4096      // edges per scatter tile
#define CAPB   9216      // ebuf bucket capacity: mu=8192, sigma~90 -> P(ovf)~1e-9
#define CAPB_ADJ 10752   // adj bucket capacity: CAPB + 512*3 align slack = 10752
#define WSTR   52        // LDS weight row stride (floats)

// bf16 helpers: storage-only quantization; accumulate in fp32.
__device__ __forceinline__ float bf2f(unsigned short u) {
    union { unsigned int i; float f; } c;
    c.i = ((unsigned int)u) << 16;
    return c.f;
}
__device__ __forceinline__ unsigned short f2bf(float f) {   // RNE
    unsigned int u = __float_as_uint(f);
    unsigned int r = u + 0x7FFFu + ((u >> 16) & 1u);
    return (unsigned short)(r >> 16);
}

// ---------------------------------------------------------------------------
// proj48: layer-1 projection, 4 threads/node. P and S both bf16 out.
// ---------------------------------------------------------------------------
__global__ __launch_bounds__(256) void proj48_kernel(
        const float* __restrict__ X,
        const float* __restrict__ Wl,
        const float* __restrict__ Wr,
        const float* __restrict__ b,
        unsigned short* __restrict__ P,
        unsigned short* __restrict__ S,
        int N) {
    __shared__ float sWl[N_HID * WSTR];
    __shared__ float sWr[N_HID * WSTR];
    __shared__ float sb[N_HID];
    int t = threadIdx.x;
    for (int idx = t; idx < N_HID * N_IN; idx += 256) {
        int r = idx / N_IN, k = idx - r * N_IN;
        sWl[r * WSTR + k] = Wl[idx];
        sWr[r * WSTR + k] = Wr[idx];
    }
    if (t < N_HID) sb[t] = b[t];
    __syncthreads();

    int node = blockIdx.x * 64 + (t >> 2);
    int q = t & 3;
    if (node >= N) return;

    const float4* xrow = reinterpret_cast<const float4*>(X + (size_t)node * N_IN);
    float accL[4], accR[4];
#pragma unroll
    for (int oo = 0; oo < 4; oo++) { accL[oo] = 0.0f; accR[oo] = sb[4 * q + oo]; }

#pragma unroll
    for (int c = 0; c < N_IN / 4; c++) {
        float4 xv = xrow[c];   // quad-mates read same addr -> broadcast
#pragma unroll
        for (int oo = 0; oo < 4; oo++) {
            int row = 4 * q + oo;
            float4 wl = *reinterpret_cast<const float4*>(&sWl[row * WSTR + 4 * c]);
            float4 wr = *reinterpret_cast<const float4*>(&sWr[row * WSTR + 4 * c]);
            accL[oo] = fmaf(xv.x, wl.x, accL[oo]); accR[oo] = fmaf(xv.x, wr.x, accR[oo]);
            accL[oo] = fmaf(xv.y, wl.y, accL[oo]); accR[oo] = fmaf(xv.y, wr.y, accR[oo]);
            accL[oo] = fmaf(xv.z, wl.z, accL[oo]); accR[oo] = fmaf(xv.z, wr.z, accR[oo]);
            accL[oo] = fmaf(xv.w, wl.w, accL[oo]); accR[oo] = fmaf(xv.w, wr.w, accR[oo]);
        }
    }

    int gid = node * 4 + q;
    reinterpret_cast<ushort4*>(P)[gid] =
        make_ushort4(f2bf(accL[0]), f2bf(accL[1]), f2bf(accL[2]), f2bf(accL[3]));
    reinterpret_cast<ushort4*>(S)[gid] =
        make_ushort4(f2bf(accR[0]), f2bf(accR[1]), f2bf(accR[2]), f2bf(accR[3]));
}

// ---------------------------------------------------------------------------
// scatter_tiles: tile-synchronous multisplit into fixed-capacity buckets
// (ebuf[b*CAPB + r]); dst cached across passes. Entry: (local_dst<<17)|src.
// ---------------------------------------------------------------------------
__global__ __launch_bounds__(256) void scatter_tiles_kernel(
        const int* __restrict__ src, const int* __restrict__ dst,
        int* __restrict__ cursor, int* __restrict__ ebuf, int E) {
    __shared__ int lh[256];
    __shared__ int gbase[256];
    __shared__ int rank[256];
    int t = threadIdx.x;
    lh[t] = 0;
    rank[t] = 0;
    __syncthreads();
    int base = blockIdx.x * TILE;
    int dcache[TILE / 256];
#pragma unroll
    for (int k = 0; k < TILE / 256; k++) {
        int e = base + t + k * 256;
        dcache[k] = -1;
        if (e < E) {
            int d = dst[e];
            dcache[k] = d;
            atomicAdd(&lh[d >> NB_SHIFT], 1);
        }
    }
    __syncthreads();
    if (lh[t]) gbase[t] = atomicAdd(&cursor[t], lh[t]);
    __syncthreads();
#pragma unroll
    for (int k = 0; k < TILE / 256; k++) {
        int e = base + t + k * 256;
        if (e < E) {
            int d = dcache[k];
            int b = d >> NB_SHIFT;
            int r = gbase[b] + atomicAdd(&rank[b], 1);
            if (r < CAPB)
                ebuf[b * CAPB + r] = ((d & 511) << 17) | src[e];
        }
    }
}

// ---------------------------------------------------------------------------
// fine_fill (2-pass, dense CSR-style): pass 1 counts per node (LDS atomics),
// LDS scan of 16B-aligned row sizes -> exact packed row offsets, write
// rs_cnt=(rowstart,cnt) int2; pass 2 re-streams ebuf (L2-hot) placing srcs.
// adj rows are dense back-to-back (16B-aligned starts) -> line-shared reads.
// ---------------------------------------------------------------------------
__global__ __launch_bounds__(256) void fine_fill_kernel(
        const int* __restrict__ cursor, const int* __restrict__ ebuf,
        int2* __restrict__ rs_cnt, int* __restrict__ adj, int N) {
    __shared__ int lc[512];
    __shared__ int lr[512];
    __shared__ int off[512];
    __shared__ int psum[256];
    int b = blockIdx.x;
    int t = threadIdx.x;
    int nodeBeg = b << NB_SHIFT;
    int adjBase = b * CAPB_ADJ;
    lc[t] = 0; lc[t + 256] = 0;
    lr[t] = 0; lr[t + 256] = 0;
    __syncthreads();

    int beg = b * CAPB;
    int nb_cnt = cursor[b];
    if (nb_cnt > CAPB) nb_cnt = CAPB;
    int end = beg + nb_cnt;
    for (int e = beg + t; e < end; e += 256)
        atomicAdd(&lc[((unsigned int)ebuf[e]) >> 17], 1);
    __syncthreads();

    // scan of aligned row sizes (2 elements/thread, Hillis-Steele on pair sums)
    int a0 = (lc[2 * t] + 3) & ~3;
    int a1 = (lc[2 * t + 1] + 3) & ~3;
    psum[t] = a0 + a1;
    __syncthreads();
#pragma unroll
    for (int d = 1; d < 256; d <<= 1) {
        int add = (t >= d) ? psum[t - d] : 0;
        __syncthreads();
        psum[t] += add;
        __syncthreads();
    }
    int pairExcl = psum[t] - (a0 + a1);
    off[2 * t] = pairExcl;
    off[2 * t + 1] = pairExcl + a0;
    __syncthreads();

    for (int i = t; i < 512; i += 256) {
        int node = nodeBeg + i;
        if (node < N) rs_cnt[node] = make_int2(adjBase + off[i], lc[i]);
    }

    for (int e = beg + t; e < end; e += 256) {
        int v = ebuf[e];
        int ld = ((unsigned int)v) >> 17;
        int s  = v & 0x1FFFF;
        int p = atomicAdd(&lr[ld], 1);
        int idx = off[ld] + p;
        if (idx < CAPB_ADJ) adj[adjBase + idx] = s;
    }
}

// ---------------------------------------------------------------------------
// fused layer-1 gather + layer-2 proj (16 -> 16). Pin/Sin bf16, outs bf16.
// ---------------------------------------------------------------------------
__global__ __launch_bounds__(256) void gather_proj16_kernel(
        const int2* __restrict__ rs_cnt, const int* __restrict__ adj,
        const unsigned short* __restrict__ Pin, const unsigned short* __restrict__ Sin,
        const float* __restrict__ Wl, const float* __restrict__ Wr,
        const float* __restrict__ bias,
        unsigned short* __restrict__ Pout, unsigned short* __restrict__ Sout, int N) {
    int gid = blockIdx.x * blockDim.x + threadIdx.x;
    if (gid >= N * 4) return;
    int i = gid >> 2;
    int q = gid & 3;
    int2 rc = rs_cnt[i];          // quad-broadcast 8B load
    int deg = rc.y;
    const int* lst = adj + rc.x;
    ushort4 svu = reinterpret_cast<const ushort4*>(Sin)[gid];
    float4 acc = make_float4(0.f, 0.f, 0.f, 0.f);
    const ushort4* P4 = reinterpret_cast<const ushort4*>(Pin);
    int e = 0;
    for (; e + 8 <= deg; e += 8) {
        int4 ja = *reinterpret_cast<const int4*>(lst + e);
        int4 jb = *reinterpret_cast<const int4*>(lst + e + 4);
        ushort4 t0 = P4[(size_t)ja.x * 4 + q];
        ushort4 t1 = P4[(size_t)ja.y * 4 + q];
        ushort4 t2 = P4[(size_t)ja.z * 4 + q];
        ushort4 t3 = P4[(size_t)ja.w * 4 + q];
        ushort4 t4 = P4[(size_t)jb.x * 4 + q];
        ushort4 t5 = P4[(size_t)jb.y * 4 + q];
        ushort4 t6 = P4[(size_t)jb.z * 4 + q];
        ushort4 t7 = P4[(size_t)jb.w * 4 + q];
        acc.x += ((bf2f(t0.x) + bf2f(t1.x)) + (bf2f(t2.x) + bf2f(t3.x)))
               + ((bf2f(t4.x) + bf2f(t5.x)) + (bf2f(t6.x) + bf2f(t7.x)));
        acc.y += ((bf2f(t0.y) + bf2f(t1.y)) + (bf2f(t2.y) + bf2f(t3.y)))
               + ((bf2f(t4.y) + bf2f(t5.y)) + (bf2f(t6.y) + bf2f(t7.y)));
        acc.z += ((bf2f(t0.z) + bf2f(t1.z)) + (bf2f(t2.z) + bf2f(t3.z)))
               + ((bf2f(t4.z) + bf2f(t5.z)) + (bf2f(t6.z) + bf2f(t7.z)));
        acc.w += ((bf2f(t0.w) + bf2f(t1.w)) + (bf2f(t2.w) + bf2f(t3.w)))
               + ((bf2f(t4.w) + bf2f(t5.w)) + (bf2f(t6.w) + bf2f(t7.w)));
    }
    for (; e + 4 <= deg; e += 4) {
        int4 js = *reinterpret_cast<const int4*>(lst + e);
        ushort4 t0 = P4[(size_t)js.x * 4 + q];
        ushort4 t1 = P4[(size_t)js.y * 4 + q];
        ushort4 t2 = P4[(size_t)js.z * 4 + q];
        ushort4 t3 = P4[(size_t)js.w * 4 + q];
        acc.x += (bf2f(t0.x) + bf2f(t1.x)) + (bf2f(t2.x) + bf2f(t3.x));
        acc.y += (bf2f(t0.y) + bf2f(t1.y)) + (bf2f(t2.y) + bf2f(t3.y));
        acc.z += (bf2f(t0.z) + bf2f(t1.z)) + (bf2f(t2.z) + bf2f(t3.z));
        acc.w += (bf2f(t0.w) + bf2f(t1.w)) + (bf2f(t2.w) + bf2f(t3.w));
    }
    for (; e < deg; e++) {
        ushort4 t = P4[(size_t)lst[e] * 4 + q];
        acc.x += bf2f(t.x); acc.y += bf2f(t.y);
        acc.z += bf2f(t.z); acc.w += bf2f(t.w);
    }
    float inv = 1.0f / (float)max(deg, 1);
    float4 h;
    h.x = acc.x * inv + bf2f(svu.x); h.y = acc.y * inv + bf2f(svu.y);
    h.z = acc.z * inv + bf2f(svu.z); h.w = acc.w * inv + bf2f(svu.w);
    h.x = h.x > 0.f ? h.x : expm1f(h.x);
    h.y = h.y > 0.f ? h.y : expm1f(h.y);
    h.z = h.z > 0.f ? h.z : expm1f(h.z);
    h.w = h.w > 0.f ? h.w : expm1f(h.w);

    // exchange: lane lb+a holds features 4a..4a+3 of node i
    int lane = threadIdx.x & 63;
    int lb = lane & ~3;
    float hv[16];
#pragma unroll
    for (int a = 0; a < 4; a++) {
        hv[4 * a + 0] = __shfl(h.x, lb + a, 64);
        hv[4 * a + 1] = __shfl(h.y, lb + a, 64);
        hv[4 * a + 2] = __shfl(h.z, lb + a, 64);
        hv[4 * a + 3] = __shfl(h.w, lb + a, 64);
    }

    const float4* Wl4 = reinterpret_cast<const float4*>(Wl);
    const float4* Wr4 = reinterpret_cast<const float4*>(Wr);
    float pl[4], sr[4];
#pragma unroll
    for (int oo = 0; oo < 4; oo++) {
        int o = 4 * q + oo;
        float aL = 0.0f, aR = bias[o];
#pragma unroll
        for (int c = 0; c < 4; c++) {
            float4 wl = Wl4[o * 4 + c];
            float4 wr = Wr4[o * 4 + c];
            aL = fmaf(hv[4 * c + 0], wl.x, aL); aR = fmaf(hv[4 * c + 0], wr.x, aR);
            aL = fmaf(hv[4 * c + 1], wl.y, aL); aR = fmaf(hv[4 * c + 1], wr.y, aR);
            aL = fmaf(hv[4 * c + 2], wl.z, aL); aR = fmaf(hv[4 * c + 2], wr.z, aR);
            aL = fmaf(hv[4 * c + 3], wl.w, aL); aR = fmaf(hv[4 * c + 3], wr.w, aR);
        }
        pl[oo] = aL; sr[oo] = aR;
    }
    reinterpret_cast<ushort4*>(Pout)[gid] =
        make_ushort4(f2bf(pl[0]), f2bf(pl[1]), f2bf(pl[2]), f2bf(pl[3]));
    reinterpret_cast<ushort4*>(Sout)[gid] =
        make_ushort4(f2bf(sr[0]), f2bf(sr[1]), f2bf(sr[2]), f2bf(sr[3]));
}

// ---------------------------------------------------------------------------
// fused layer-2 gather + layer-3 proj (16 -> 8). All staging bf16.
// ---------------------------------------------------------------------------
__global__ __launch_bounds__(256) void gather_proj8_kernel(
        const int2* __restrict__ rs_cnt, const int* __restrict__ adj,
        const unsigned short* __restrict__ Pin, const unsigned short* __restrict__ Sin,
        const float* __restrict__ Wl, const float* __restrict__ Wr,
        const float* __restrict__ bias,
        unsigned short* __restrict__ Pout, unsigned short* __restrict__ Sout, int N) {
    int gid = blockIdx.x * blockDim.x + threadIdx.x;
    if (gid >= N * 4) return;
    int i = gid >> 2;
    int q = gid & 3;
    int2 rc = rs_cnt[i];
    int deg = rc.y;
    const int* lst = adj + rc.x;
    ushort4 svu = reinterpret_cast<const ushort4*>(Sin)[gid];
    float4 acc = make_float4(0.f, 0.f, 0.f, 0.f);
    const ushort4* P4 = reinterpret_cast<const ushort4*>(Pin);
    int e = 0;
    for (; e + 8 <= deg; e += 8) {
        int4 ja = *reinterpret_cast<const int4*>(lst + e);
        int4 jb = *reinterpret_cast<const int4*>(lst + e + 4);
        ushort4 t0 = P4[(size_t)ja.x * 4 + q];
        ushort4 t1 = P4[(size_t)ja.y * 4 + q];
        ushort4 t2 = P4[(size_t)ja.z * 4 + q];
        ushort4 t3 = P4[(size_t)ja.w * 4 + q];
        ushort4 t4 = P4[(size_t)jb.x * 4 + q];
        ushort4 t5 = P4[(size_t)jb.y * 4 + q];
        ushort4 t6 = P4[(size_t)jb.z * 4 + q];
        ushort4 t7 = P4[(size_t)jb.w * 4 + q];
        acc.x += ((bf2f(t0.x) + bf2f(t1.x)) + (bf2f(t2.x) + bf2f(t3.x)))
               + ((bf2f(t4.x) + bf2f(t5.x)) + (bf2f(t6.x) + bf2f(t7.x)));
        acc.y += ((bf2f(t0.y) + bf2f(t1.y)) + (bf2f(t2.y) + bf2f(t3.y)))
               + ((bf2f(t4.y) + bf2f(t5.y)) + (bf2f(t6.y) + bf2f(t7.y)));
        acc.z += ((bf2f(t0.z) + bf2f(t1.z)) + (bf2f(t2.z) + bf2f(t3.z)))
               + ((bf2f(t4.z) + bf2f(t5.z)) + (bf2f(t6.z) + bf2f(t7.z)));
        acc.w += ((bf2f(t0.w) + bf2f(t1.w)) + (bf2f(t2.w) + bf2f(t3.w)))
               + ((bf2f(t4.w) + bf2f(t5.w)) + (bf2f(t6.w) + bf2f(t7.w)));
    }
    for (; e + 4 <= deg; e += 4) {
        int4 js = *reinterpret_cast<const int4*>(lst + e);
        ushort4 t0 = P4[(size_t)js.x * 4 + q];
        ushort4 t1 = P4[(size_t)js.y * 4 + q];
        ushort4 t2 = P4[(size_t)js.z * 4 + q];
        ushort4 t3 = P4[(size_t)js.w * 4 + q];
        acc.x += (bf2f(t0.x) + bf2f(t1.x)) + (bf2f(t2.x) + bf2f(t3.x));
        acc.y += (bf2f(t0.y) + bf2f(t1.y)) + (bf2f(t2.y) + bf2f(t3.y));
        acc.z += (bf2f(t0.z) + bf2f(t1.z)) + (bf2f(t2.z) + bf2f(t3.z));
        acc.w += (bf2f(t0.w) + bf2f(t1.w)) + (bf2f(t2.w) + bf2f(t3.w));
    }
    for (; e < deg; e++) {
        ushort4 t = P4[(size_t)lst[e] * 4 + q];
        acc.x += bf2f(t.x); acc.y += bf2f(t.y);
        acc.z += bf2f(t.z); acc.w += bf2f(t.w);
    }
    float inv = 1.0f / (float)max(deg, 1);
    float4 h;
    h.x = acc.x * inv + bf2f(svu.x); h.y = acc.y * inv + bf2f(svu.y);
    h.z = acc.z * inv + bf2f(svu.z); h.w = acc.w * inv + bf2f(svu.w);
    h.x = h.x > 0.f ? h.x : expm1f(h.x);
    h.y = h.y > 0.f ? h.y : expm1f(h.y);
    h.z = h.z > 0.f ? h.z : expm1f(h.z);
    h.w = h.w > 0.f ? h.w : expm1f(h.w);

    int lane = threadIdx.x & 63;
    int lb = lane & ~3;
    float hv[16];
#pragma unroll
    for (int a = 0; a < 4; a++) {
        hv[4 * a + 0] = __shfl(h.x, lb + a, 64);
        hv[4 * a + 1] = __shfl(h.y, lb + a, 64);
        hv[4 * a + 2] = __shfl(h.z, lb + a, 64);
        hv[4 * a + 3] = __shfl(h.w, lb + a, 64);
    }

    const float4* Wl4 = reinterpret_cast<const float4*>(Wl);  // [8][4]
    const float4* Wr4 = reinterpret_cast<const float4*>(Wr);
    float pl[2], sr[2];
#pragma unroll
    for (int oo = 0; oo < 2; oo++) {
        int o = 2 * q + oo;
        float aL = 0.0f, aR = bias[o];
#pragma unroll
        for (int c = 0; c < 4; c++) {
            float4 wl = Wl4[o * 4 + c];
            float4 wr = Wr4[o * 4 + c];
            aL = fmaf(hv[4 * c + 0], wl.x, aL); aR = fmaf(hv[4 * c + 0], wr.x, aR);
            aL = fmaf(hv[4 * c + 1], wl.y, aL); aR = fmaf(hv[4 * c + 1], wr.y, aR);
            aL = fmaf(hv[4 * c + 2], wl.z, aL); aR = fmaf(hv[4 * c + 2], wr.z, aR);
            aL = fmaf(hv[4 * c + 3], wl.w, aL); aR = fmaf(hv[4 * c + 3], wr.w, aR);
        }
        pl[oo] = aL; sr[oo] = aR;
    }
    reinterpret_cast<unsigned int*>(Pout)[gid] =
        ((unsigned int)f2bf(pl[1]) << 16) | f2bf(pl[0]);
    reinterpret_cast<unsigned int*>(Sout)[gid] =
        ((unsigned int)f2bf(sr[1]) << 16) | f2bf(sr[0]);
}

// ---------------------------------------------------------------------------
// gather8 + log_softmax. Pin/Sin bf16; fp32 output.
// ---------------------------------------------------------------------------
__global__ __launch_bounds__(256) void gather8_kernel(
        const int2* __restrict__ rs_cnt, const int* __restrict__ adj,
        const unsigned short* __restrict__ P, const unsigned short* __restrict__ S,
        float* __restrict__ out, int N) {
    int gid = blockIdx.x * blockDim.x + threadIdx.x;
    if (gid >= N * 2) return;
    int i = gid >> 1;
    int q = gid & 1;
    int2 rc = rs_cnt[i];
    int deg = rc.y;
    const int* lst = adj + rc.x;
    ushort4 svu = reinterpret_cast<const ushort4*>(S)[gid];
    float4 acc = make_float4(0.f, 0.f, 0.f, 0.f);
    const ushort4* P4 = reinterpret_cast<const ushort4*>(P);
    int e = 0;
    for (; e + 8 <= deg; e += 8) {
        int4 ja = *reinterpret_cast<const int4*>(lst + e);
        int4 jb = *reinterpret_cast<const int4*>(lst + e + 4);
        ushort4 t0 = P4[(size_t)ja.x * 2 + q];
        ushort4 t1 = P4[(size_t)ja.y * 2 + q];
        ushort4 t2 = P4[(size_t)ja.z * 2 + q];
        ushort4 t3 = P4[(size_t)ja.w * 2 + q];
        ushort4 t4 = P4[(size_t)jb.x * 2 + q];
        ushort4 t5 = P4[(size_t)jb.y * 2 + q];
        ushort4 t6 = P4[(size_t)jb.z * 2 + q];
        ushort4 t7 = P4[(size_t)jb.w * 2 + q];
        acc.x += ((bf2f(t0.x) + bf2f(t1.x)) + (bf2f(t2.x) + bf2f(t3.x)))
               + ((bf2f(t4.x) + bf2f(t5.x)) + (bf2f(t6.x) + bf2f(t7.x)));
        acc.y += ((bf2f(t0.y) + bf2f(t1.y)) + (bf2f(t2.y) + bf2f(t3.y)))
               + ((bf2f(t4.y) + bf2f(t5.y)) + (bf2f(t6.y) + bf2f(t7.y)));
        acc.z += ((bf2f(t0.z) + bf2f(t1.z)) + (bf2f(t2.z) + bf2f(t3.z)))
               + ((bf2f(t4.z) + bf2f(t5.z)) + (bf2f(t6.z) + bf2f(t7.z)));
        acc.w += ((bf2f(t0.w) + bf2f(t1.w)) + (bf2f(t2.w) + bf2f(t3.w)))
               + ((bf2f(t4.w) + bf2f(t5.w)) + (bf2f(t6.w) + bf2f(t7.w)));
    }
    for (; e + 4 <= deg; e += 4) {
        int4 js = *reinterpret_cast<const int4*>(lst + e);
        ushort4 t0 = P4[(size_t)js.x * 2 + q];
        ushort4 t1 = P4[(size_t)js.y * 2 + q];
        ushort4 t2 = P4[(size_t)js.z * 2 + q];
        ushort4 t3 = P4[(size_t)js.w * 2 + q];
        acc.x += (bf2f(t0.x) + bf2f(t1.x)) + (bf2f(t2.x) + bf2f(t3.x));
        acc.y += (bf2f(t0.y) + bf2f(t1.y)) + (bf2f(t2.y) + bf2f(t3.y));
        acc.z += (bf2f(t0.z) + bf2f(t1.z)) + (bf2f(t2.z) + bf2f(t3.z));
        acc.w += (bf2f(t0.w) + bf2f(t1.w)) + (bf2f(t2.w) + bf2f(t3.w));
    }
    for (; e < deg; e++) {
        ushort4 t = P4[(size_t)lst[e] * 2 + q];
        acc.x += bf2f(t.x); acc.y += bf2f(t.y);
        acc.z += bf2f(t.z); acc.w += bf2f(t.w);
    }
    float inv = 1.0f / (float)max(deg, 1);
    float4 v;
    v.x = acc.x * inv + bf2f(svu.x); v.y = acc.y * inv + bf2f(svu.y);
    v.z = acc.z * inv + bf2f(svu.z); v.w = acc.w * inv + bf2f(svu.w);
    v.x = v.x > 0.f ? v.x : expm1f(v.x);
    v.y = v.y > 0.f ? v.y : expm1f(v.y);
    v.z = v.z > 0.f ? v.z : expm1f(v.z);
    v.w = v.w > 0.f ? v.w : expm1f(v.w);
    float m = fmaxf(fmaxf(v.x, v.y), fmaxf(v.z, v.w));
    m = fmaxf(m, __shfl_xor(m, 1));
    float sum = expf(v.x - m) + expf(v.y - m) + expf(v.z - m) + expf(v.w - m);
    sum += __shfl_xor(sum, 1);
    float lse = m + logf(sum);
    reinterpret_cast<float4*>(out)[gid] =
        make_float4(v.x - lse, v.y - lse, v.z - lse, v.w - lse);
}

extern "C" void kernel_launch(void* const* d_in, const int* in_sizes, int n_in,
                              void* d_out, int out_size, void* d_ws, size_t ws_size,
                              hipStream_t stream) {
    const float* x   = (const float*)d_in[0];
    const int*   ei  = (const int*)d_in[1];
    const float* W1l = (const float*)d_in[2];
    const float* W1r = (const float*)d_in[3];
    const float* b1  = (const float*)d_in[4];
    const float* W2l = (const float*)d_in[5];
    const float* W2r = (const float*)d_in[6];
    const float* b2  = (const float*)d_in[7];
    const float* W3l = (const float*)d_in[8];
    const float* W3r = (const float*)d_in[9];
    const float* b3  = (const float*)d_in[10];
    float* out = (float*)d_out;

    const int N = in_sizes[0] / N_IN;
    const int E = in_sizes[1] / 2;
    const int* src = ei;
    const int* dst = ei + E;
    const int nbuck = (N + 511) >> NB_SHIFT;   // 196

    // Workspace:
    //  [cursor 256 int][rs_cnt N int2][adj nbuck*CAPB_ADJ int]
    //  [P1 bf16 N*16][P2 bf16 N*16][S1 bf16 N*16][S3 bf16 N*8]
    // ebuf (int, nbuck*CAPB = 7.2 MB) aliases P1..S1 (9.6 MB; dead during
    // build). P3 (bf16 N*8) aliases P1 after gather_proj16 consumes it.
    // S2 == S1 in place.
    int*  cursor = (int*)d_ws;
    int2* rs_cnt = (int2*)(cursor + 256);
    int*  adj    = (int*)(rs_cnt + N);
    unsigned short* P1 = (unsigned short*)(adj + (size_t)nbuck * CAPB_ADJ);
    unsigned short* P2 = P1 + (size_t)N * N_HID;
    unsigned short* S1 = P2 + (size_t)N * N_HID;
    unsigned short* S3 = S1 + (size_t)N * N_HID;
    int* ebuf = (int*)P1;
    unsigned short* P3 = P1;

    hipMemsetAsync(cursor, 0, 256 * sizeof(int), stream);

    const int B = 256;
    int n4Grid   = (N * 4 + B - 1) / B;
    int n2Grid   = (N * 2 + B - 1) / B;
    int p1Grid   = (N + 63) / 64;
    int tileGrid = (E + TILE - 1) / TILE;

    // ---- adjacency build: grouped scatter -> dense CSR-style fill ----
    scatter_tiles_kernel<<<tileGrid, B, 0, stream>>>(src, dst, cursor, ebuf, E);
    fine_fill_kernel<<<nbuck, B, 0, stream>>>(cursor, ebuf, rs_cnt, adj, N);

    // ---- Layer 1 proj: 48 -> 16 (P1, S1 bf16) ----
    proj48_kernel<<<p1Grid, B, 0, stream>>>(x, W1l, W1r, b1, P1, S1, N);

    // ---- Layer-1 gather + layer-2 proj: P2, S2=S1 in place ----
    gather_proj16_kernel<<<n4Grid, B, 0, stream>>>(rs_cnt, adj, P1, S1,
                                                   W2l, W2r, b2, P2, S1, N);

    // ---- Layer-2 gather + layer-3 proj: P3 (aliases P1), S3 ----
    gather_proj8_kernel<<<n4Grid, B, 0, stream>>>(rs_cnt, adj, P2, S1,
                                                  W3l, W3r, b3, P3, S3, N);

    // ---- Layer 3 gather + log_softmax ----
    gather8_kernel<<<n2Grid, B, 0, stream>>>(rs_cnt, adj, P3, S3, out, N);
}